// Round 5
// baseline (337.698 us; speedup 1.0000x reference)
//
#include <hip/hip_runtime.h>

#define B_  64
#define T_  1000
#define DV_ 512
#define DQ_ 1024
#define U_  128
#define F_  32
#define KS_ 31
#define P_  16     // context partial chunks per batch
#define CT_ 63     // t per chunk (last chunk 55)

typedef __attribute__((ext_vector_type(8))) short short8;
typedef __attribute__((ext_vector_type(4))) float f32x4;

// round-to-nearest-even f32 -> bf16 (bit trick), packed pair
__device__ __forceinline__ unsigned pk2(float a, float b) {
    union { float f; unsigned u; } x, y;
    x.f = a; y.f = b;
    unsigned ra = (x.u + 0x7FFFu + ((x.u >> 16) & 1u)) >> 16;
    unsigned rb = (y.u + 0x7FFFu + ((y.u >> 16) & 1u)) >> 16;
    return (ra & 0xFFFFu) | (rb << 16);
}

__device__ __forceinline__ float fast_tanh(float x) {
    return 1.0f - 2.0f / (__expf(2.0f * x) + 1.0f);
}

// pack two float4 (8 consecutive k) into bf16 short8
__device__ __forceinline__ short8 pk8(float4 f0, float4 f1) {
    int4 q;
    q.x = pk2(f0.x, f0.y); q.y = pk2(f0.z, f0.w);
    q.z = pk2(f1.x, f1.y); q.w = pk2(f1.z, f1.w);
    return *(short8*)&q;
}

// async global->LDS DMA, 16B per lane; LDS dest is wave-uniform base + lane*16
__device__ __forceinline__ void gload_lds16(const void* g, void* l) {
    __builtin_amdgcn_global_load_lds(
        (const __attribute__((address_space(1))) unsigned*)g,
        (__attribute__((address_space(3))) unsigned*)l, 16, 0, 0);
}

// ---------------------------------------------------------------------------
// Merged: prep (repack Wm/Wl to bf16 B-frag layout) + qb (query proj).
// Blocks 0..8: prep. Blocks 9..72: qb for b = blk-9.
// ---------------------------------------------------------------------------
__global__ __launch_bounds__(1024) void prep_qb_kernel(
    const float* __restrict__ Wm, const float* __restrict__ Wl,
    const float* __restrict__ query, const float* __restrict__ Wq,
    const float* __restrict__ bq, const float* __restrict__ bm,
    short* __restrict__ WmX, short* __restrict__ WlX, float* __restrict__ qb)
{
    __shared__ float sh[DQ_ + 8 * U_];
    int blk = blockIdx.x, tid = threadIdx.x;
    if (blk < 9) {
        int g = blk * 1024 + tid;
        if (g < 8192) {
            int kc = g >> 9, e = g & 511;
            int n = e >> 2, q = e & 3;
            int kb = kc * 32 + q * 8;
            int4 p;
            p.x = pk2(Wm[(kb + 0) * U_ + n], Wm[(kb + 1) * U_ + n]);
            p.y = pk2(Wm[(kb + 2) * U_ + n], Wm[(kb + 3) * U_ + n]);
            p.z = pk2(Wm[(kb + 4) * U_ + n], Wm[(kb + 5) * U_ + n]);
            p.w = pk2(Wm[(kb + 6) * U_ + n], Wm[(kb + 7) * U_ + n]);
            ((int4*)WmX)[g] = p;
        } else if (g < 8704) {
            int e = g - 8192;
            int n = e >> 2, q = e & 3;
            int kb = q * 8;
            int4 p;
            p.x = pk2(Wl[(kb + 0) * U_ + n], Wl[(kb + 1) * U_ + n]);
            p.y = pk2(Wl[(kb + 2) * U_ + n], Wl[(kb + 3) * U_ + n]);
            p.z = pk2(Wl[(kb + 4) * U_ + n], Wl[(kb + 5) * U_ + n]);
            p.w = pk2(Wl[(kb + 6) * U_ + n], Wl[(kb + 7) * U_ + n]);
            ((int4*)WlX)[e] = p;
        }
    } else {
        float* qs = sh;
        float* red = sh + DQ_;
        int b = blk - 9;
        qs[tid] = query[b * DQ_ + tid];
        __syncthreads();
        int u = tid & 127, p = tid >> 7;
        float a = 0.f;
        const float* wp = Wq + (size_t)p * 128 * U_ + u;
        const float* qp = qs + p * 128;
#pragma unroll 8
        for (int k = 0; k < 128; ++k) a += qp[k] * wp[(size_t)k * U_];
        red[p * U_ + u] = a;
        __syncthreads();
        if (tid < U_) {
            float s = bq[tid] + bm[tid];
#pragma unroll
            for (int pp = 0; pp < 8; ++pp) s += red[pp * U_ + tid];
            qb[b * U_ + tid] = s;
        }
    }
}

// ---------------------------------------------------------------------------
// scores[r], r=b*T+t: tanh(values@Wm + qb + tanh(conv(prev)@Wl)) @ Wv + bv
// M=64/block (1000 blocks). A staged fp32 via global_load_lds (16B units),
// double-buffered BK=64 tiles, rotation swizzle (unit + (row&7)) folded into
// DMA src addrs -> conflict-free frag reads. B at-use from L2-hot WmX.
// LDS: AsL/WcS aliased onto As1 -> ~34KB, 4 blocks/CU.
// ---------------------------------------------------------------------------
__global__ __launch_bounds__(256, 4) void score_kernel(
    const float* __restrict__ values, const float* __restrict__ prev,
    const float* __restrict__ Wc, const float* __restrict__ Wv,
    const float* __restrict__ bv, const short* __restrict__ WmX,
    const short* __restrict__ WlX, const float* __restrict__ qb,
    float* __restrict__ scores)
{
    __shared__ char smem[2 * 16384 + 1024 + 512];
    float* As0 = (float*)smem;                      // 16 KB buf 0
    float* As1 = (float*)(smem + 16384);            // 16 KB buf 1
    short* AsL = (short*)(smem + 16384);            // alias on As1 (4 KB)
    float* WcS = (float*)(smem + 16384 + 4096);     // alias on As1 (3.9 KB)
    float* qbS = (float*)(smem + 32768);            // 1 KB
    float* WvS = (float*)(smem + 32768 + 1024);     // 0.5 KB

    const int tid = threadIdx.x;
    const int r0 = blockIdx.x * 64;
    const int b0 = r0 / T_;
    const int b1 = (r0 + 63) / T_;

    const int wv = tid >> 6, lane = tid & 63;
    const int quad = lane >> 4, m15 = lane & 15;
    const int row = wv * 16 + m15;
    const int lrow = lane >> 4;                     // staging: row within 4-row group

    const int4* bW  = (const int4*)WmX + m15 * 4 + quad;
    const int4* blW = (const int4*)WlX + m15 * 4 + quad;

    // stage: DMA 64 rows x 64 floats [k0,k0+64) into dst.
    // lane i of instr j fetches SRC unit ((i&15) + R) & 15, R = (j&1)*4 + lrow,
    // so LDS unit u of row r holds src unit (u + (r&7)) & 15.
    auto stage = [&](float* dst, int k0) {
#pragma unroll
        for (int j = 0; j < 4; ++j) {
            int R = ((j & 1) << 2) + lrow;
            int lu = ((lane & 15) + R) & 15;
            const float* src = values + (size_t)(r0 + wv * 16 + j * 4 + lrow) * DV_
                               + k0 + lu * 4;
            gload_lds16(src, dst + (wv * 16 + j * 4) * 64);
        }
    };

    stage(As0, 0);   // in flight across conv

    for (int i = tid; i < KS_ * F_; i += 256) WcS[i] = Wc[i];
    if (tid < U_) WvS[tid] = Wv[tid];
    {
        int bb = (tid < U_) ? b0 : b1;
        qbS[tid] = qb[bb * U_ + (tid & (U_ - 1))];
    }
    __syncthreads();   // WcS/qbS/WvS ready (also drains As0 DMA)

    // location conv: loc_pre[i,f] = sum_k prev[b, t+k-15]*Wc[k,f] (SAME pad)
    {
        int i = tid & 63, fg = tid >> 6;
        int r = r0 + i;
        int b = r / T_;
        int t = r - b * T_;
        const float* pv = prev + b * T_;
        float a8[8] = {};
#pragma unroll
        for (int k = 0; k < KS_; ++k) {
            int tt = t + k - 15;
            float p = ((unsigned)tt < (unsigned)T_) ? pv[tt] : 0.f;
#pragma unroll
            for (int j = 0; j < 8; ++j) a8[j] += p * WcS[k * F_ + fg * 8 + j];
        }
        int4 pq;
        pq.x = pk2(a8[0], a8[1]); pq.y = pk2(a8[2], a8[3]);
        pq.z = pk2(a8[4], a8[5]); pq.w = pk2(a8[6], a8[7]);
        ((int4*)AsL)[i * 4 + (fg ^ ((i >> 1) & 3))] = pq;
    }
    __syncthreads();

    // loc GEMM (K=32) -> acc init = qb + tanh(loc)
    f32x4 acc[8] = {};
    {
        short8 afl = ((const short8*)AsL)[row * 4 + (quad ^ ((row >> 1) & 3))];
#pragma unroll
        for (int c = 0; c < 8; ++c) {
            int4 bl = blW[c * 64];
            acc[c] = __builtin_amdgcn_mfma_f32_16x16x32_bf16(afl, *(short8*)&bl, acc[c], 0, 0, 0);
        }
        int qoff[4];
#pragma unroll
        for (int v = 0; v < 4; ++v) {
            int r = r0 + wv * 16 + quad * 4 + v;
            qoff[v] = ((r / T_) == b0) ? 0 : U_;
        }
#pragma unroll
        for (int c = 0; c < 8; ++c) {
            int col = c * 16 + m15;
#pragma unroll
            for (int v = 0; v < 4; ++v)
                acc[c][v] = qbS[qoff[v] + col] + fast_tanh(acc[c][v]);
        }
    }
    __syncthreads();   // AsL/WcS reads done -> As1 region reusable

    // main loop: 8 steps x BK=64 (2 kc each); one barrier per step
    const int Rr = m15 & 7;   // read-side rotation
#pragma unroll
    for (int s = 0; s < 8; ++s) {
        if (s < 7) stage((s & 1) ? As0 : As1, (s + 1) * 64);
        const float4* ap = (const float4*)(((s & 1) ? As1 : As0) + row * 64);
        int4 bf[8];
        // kc = 0
#pragma unroll
        for (int c = 0; c < 8; ++c) bf[c] = bW[(2 * s) * 512 + c * 64];
        {
            int x = quad * 2;
            float4 f0 = ap[(x - Rr) & 15];
            float4 f1 = ap[(x + 1 - Rr) & 15];
            short8 af = pk8(f0, f1);
#pragma unroll
            for (int c = 0; c < 8; ++c)
                acc[c] = __builtin_amdgcn_mfma_f32_16x16x32_bf16(af, *(short8*)&bf[c], acc[c], 0, 0, 0);
        }
        // kc = 1
#pragma unroll
        for (int c = 0; c < 8; ++c) bf[c] = bW[(2 * s + 1) * 512 + c * 64];
        {
            int x = 8 + quad * 2;
            float4 f0 = ap[(x - Rr) & 15];
            float4 f1 = ap[(x + 1 - Rr) & 15];
            short8 af = pk8(f0, f1);
#pragma unroll
            for (int c = 0; c < 8; ++c)
                acc[c] = __builtin_amdgcn_mfma_f32_16x16x32_bf16(af, *(short8*)&bf[c], acc[c], 0, 0, 0);
        }
        __syncthreads();
    }

    // epilogue: score = sum_col tanh(acc)*Wv[col] + bv
    float psum[4] = {0.f, 0.f, 0.f, 0.f};
#pragma unroll
    for (int c = 0; c < 8; ++c) {
        int col = c * 16 + m15;
        float wvv = WvS[col];
#pragma unroll
        for (int v = 0; v < 4; ++v)
            psum[v] += fast_tanh(acc[c][v]) * wvv;
    }
#pragma unroll
    for (int off = 1; off < 16; off <<= 1) {
#pragma unroll
        for (int v = 0; v < 4; ++v) psum[v] += __shfl_xor(psum[v], off);
    }
    if (m15 == 0) {
        float bvv = bv[0];
#pragma unroll
        for (int v = 0; v < 4; ++v)
            scores[r0 + wv * 16 + quad * 4 + v] = psum[v] + bvv;
    }
}

// ---------------------------------------------------------------------------
// fused softmax + context partial. grid (64, 16). Each block recomputes the
// softmax stats from scores (L2-hot, 4KB), writes its attw t-slice, and
// accumulates partial context over its 63-t chunk.
// ---------------------------------------------------------------------------
__global__ __launch_bounds__(256) void ctxsm_kernel(
    const float* __restrict__ scores, const float* __restrict__ values,
    float* __restrict__ attw, float* __restrict__ part)
{
    __shared__ float sS[1024];
    __shared__ float red[4];
    __shared__ float4 ps[128];
    int b = blockIdx.x, p = blockIdx.y, tid = threadIdx.x;
    const float* sb = scores + b * T_;
    float v[4];
#pragma unroll
    for (int i = 0; i < 4; ++i) {
        int t = tid + i * 256;
        v[i] = (t < T_) ? sb[t] : -1e30f;
        sS[t] = v[i];
    }
    float mx = fmaxf(fmaxf(v[0], v[1]), fmaxf(v[2], v[3]));
#pragma unroll
    for (int off = 32; off >= 1; off >>= 1) mx = fmaxf(mx, __shfl_xor(mx, off));
    int wvi = tid >> 6, lane = tid & 63;
    if (lane == 0) red[wvi] = mx;
    __syncthreads();
    mx = fmaxf(fmaxf(red[0], red[1]), fmaxf(red[2], red[3]));
    float sum = 0.f;
#pragma unroll
    for (int i = 0; i < 4; ++i)
        sum += (tid + i * 256 < T_) ? __expf(v[i] - mx) : 0.f;
#pragma unroll
    for (int off = 32; off >= 1; off >>= 1) sum += __shfl_xor(sum, off);
    __syncthreads();
    if (lane == 0) red[wvi] = sum;
    __syncthreads();
    float inv = 1.0f / (red[0] + red[1] + red[2] + red[3]);

    int t0 = p * CT_;
    int len = (T_ - t0 < CT_) ? (T_ - t0) : CT_;
    if (tid < len) attw[b * T_ + t0 + tid] = __expf(sS[t0 + tid] - mx) * inv;

    int cl = tid & 127, tp = tid >> 7;
    const float* vp = values + ((size_t)b * T_ + t0) * DV_ + cl * 4;
    float4 a = {0.f, 0.f, 0.f, 0.f};
#pragma unroll 4
    for (int t = tp; t < len; t += 2) {
        float4 vv = *(const float4*)(vp + (size_t)t * DV_);
        float wt = __expf(sS[t0 + t] - mx) * inv;
        a.x += wt * vv.x; a.y += wt * vv.y; a.z += wt * vv.z; a.w += wt * vv.w;
    }
    if (tp == 1) ps[cl] = a;
    __syncthreads();
    if (tp == 0) {
        float4 o = ps[cl];
        o.x += a.x; o.y += a.y; o.z += a.z; o.w += a.w;
        *(float4*)(part + ((size_t)(b * P_ + p)) * DV_ + cl * 4) = o;
    }
}

// context phase 2: ctx[b,d] = sum_p partial[b,p,d]
__global__ void ctx2_kernel(const float* __restrict__ part, float* __restrict__ ctx) {
    int b = blockIdx.x, tid = threadIdx.x;   // 128 threads, float4 each
    const float* pp = part + (size_t)b * P_ * DV_ + tid * 4;
    float4 s = {0.f, 0.f, 0.f, 0.f};
#pragma unroll
    for (int p = 0; p < P_; ++p) {
        float4 v = *(const float4*)(pp + (size_t)p * DV_);
        s.x += v.x; s.y += v.y; s.z += v.z; s.w += v.w;
    }
    *(float4*)(ctx + (size_t)b * DV_ + tid * 4) = s;
}

extern "C" void kernel_launch(void* const* d_in, const int* in_sizes, int n_in,
                              void* d_out, int out_size, void* d_ws, size_t ws_size,
                              hipStream_t stream) {
    const float* query  = (const float*)d_in[0];
    const float* values = (const float*)d_in[1];
    const float* prev   = (const float*)d_in[2];
    const float* Wq     = (const float*)d_in[3];
    const float* bq     = (const float*)d_in[4];
    const float* Wm     = (const float*)d_in[5];
    const float* bm     = (const float*)d_in[6];
    const float* Wv     = (const float*)d_in[7];
    const float* bv     = (const float*)d_in[8];
    const float* Wc     = (const float*)d_in[9];
    const float* Wl     = (const float*)d_in[10];

    float* out  = (float*)d_out;
    float* ctx  = out;                 // [64,512]
    float* attw = out + B_ * DV_;      // [64,1000,1]

    char* ws = (char*)d_ws;
    float* qb     = (float*)(ws);                              // 32768 B
    float* scores = (float*)(ws + 32768);                      // 256000 B
    short* WmX    = (short*)(ws + 288768);                     // 131072 B
    short* WlX    = (short*)(ws + 419840);                     // 8192 B
    float* part   = (float*)(ws + 428032);                     // 2 MB

    prep_qb_kernel<<<73, 1024, 0, stream>>>(Wm, Wl, query, Wq, bq, bm, WmX, WlX, qb);
    score_kernel<<<1000, 256, 0, stream>>>(values, prev, Wc, Wv, bv, WmX, WlX, qb, scores);
    ctxsm_kernel<<<dim3(B_, P_), 256, 0, stream>>>(scores, values, attw, part);
    ctx2_kernel<<<B_, 128, 0, stream>>>(part, ctx);
}

// Round 6
// 318.596 us; speedup vs baseline: 1.0600x; 1.0600x over previous
//
#include <hip/hip_runtime.h>

#define B_  64
#define T_  1000
#define DV_ 512
#define DQ_ 1024
#define U_  128
#define F_  32
#define KS_ 31
#define P_  16     // context partial chunks per batch
#define CT_ 63     // t per chunk (last chunk 55)

typedef __attribute__((ext_vector_type(8))) short short8;
typedef __attribute__((ext_vector_type(4))) float f32x4;

// round-to-nearest-even f32 -> bf16 (bit trick), packed pair
__device__ __forceinline__ unsigned pk2(float a, float b) {
    union { float f; unsigned u; } x, y;
    x.f = a; y.f = b;
    unsigned ra = (x.u + 0x7FFFu + ((x.u >> 16) & 1u)) >> 16;
    unsigned rb = (y.u + 0x7FFFu + ((y.u >> 16) & 1u)) >> 16;
    return (ra & 0xFFFFu) | (rb << 16);
}

__device__ __forceinline__ float fast_tanh(float x) {
    return 1.0f - 2.0f / (__expf(2.0f * x) + 1.0f);
}

// pack two float4 (8 consecutive k) into bf16 short8
__device__ __forceinline__ short8 pk8(float4 f0, float4 f1) {
    int4 q;
    q.x = pk2(f0.x, f0.y); q.y = pk2(f0.z, f0.w);
    q.z = pk2(f1.x, f1.y); q.w = pk2(f1.z, f1.w);
    return *(short8*)&q;
}

// async global->LDS DMA, 16B per lane; LDS dest is wave-uniform base + lane*16
__device__ __forceinline__ void gload_lds16(const void* g, void* l) {
    __builtin_amdgcn_global_load_lds(
        (const __attribute__((address_space(1))) unsigned*)g,
        (__attribute__((address_space(3))) unsigned*)l, 16, 0, 0);
}

// ---------------------------------------------------------------------------
// Merged: prep (repack Wm/Wl to bf16 B-frag layout) + qb (query proj).
// Blocks 0..8: prep. Blocks 9..72: qb for b = blk-9.
// ---------------------------------------------------------------------------
__global__ __launch_bounds__(1024) void prep_qb_kernel(
    const float* __restrict__ Wm, const float* __restrict__ Wl,
    const float* __restrict__ query, const float* __restrict__ Wq,
    const float* __restrict__ bq, const float* __restrict__ bm,
    short* __restrict__ WmX, short* __restrict__ WlX, float* __restrict__ qb)
{
    __shared__ float sh[DQ_ + 8 * U_];
    int blk = blockIdx.x, tid = threadIdx.x;
    if (blk < 9) {
        int g = blk * 1024 + tid;
        if (g < 8192) {
            int kc = g >> 9, e = g & 511;
            int n = e >> 2, q = e & 3;
            int kb = kc * 32 + q * 8;
            int4 p;
            p.x = pk2(Wm[(kb + 0) * U_ + n], Wm[(kb + 1) * U_ + n]);
            p.y = pk2(Wm[(kb + 2) * U_ + n], Wm[(kb + 3) * U_ + n]);
            p.z = pk2(Wm[(kb + 4) * U_ + n], Wm[(kb + 5) * U_ + n]);
            p.w = pk2(Wm[(kb + 6) * U_ + n], Wm[(kb + 7) * U_ + n]);
            ((int4*)WmX)[g] = p;
        } else if (g < 8704) {
            int e = g - 8192;
            int n = e >> 2, q = e & 3;
            int kb = q * 8;
            int4 p;
            p.x = pk2(Wl[(kb + 0) * U_ + n], Wl[(kb + 1) * U_ + n]);
            p.y = pk2(Wl[(kb + 2) * U_ + n], Wl[(kb + 3) * U_ + n]);
            p.z = pk2(Wl[(kb + 4) * U_ + n], Wl[(kb + 5) * U_ + n]);
            p.w = pk2(Wl[(kb + 6) * U_ + n], Wl[(kb + 7) * U_ + n]);
            ((int4*)WlX)[e] = p;
        }
    } else {
        float* qs = sh;
        float* red = sh + DQ_;
        int b = blk - 9;
        qs[tid] = query[b * DQ_ + tid];
        __syncthreads();
        int u = tid & 127, p = tid >> 7;
        float a = 0.f;
        const float* wp = Wq + (size_t)p * 128 * U_ + u;
        const float* qp = qs + p * 128;
#pragma unroll 8
        for (int k = 0; k < 128; ++k) a += qp[k] * wp[(size_t)k * U_];
        red[p * U_ + u] = a;
        __syncthreads();
        if (tid < U_) {
            float s = bq[tid] + bm[tid];
#pragma unroll
            for (int pp = 0; pp < 8; ++pp) s += red[pp * U_ + tid];
            qb[b * U_ + tid] = s;
        }
    }
}

// ---------------------------------------------------------------------------
// scores[r], r=b*T+t: tanh(values@Wm + qb + tanh(conv(prev)@Wl)) @ Wv + bv
// M=64/block (1000 blocks). A staged fp32 via global_load_lds (16B units),
// double-buffered BK=64 tiles, rotation swizzle (unit + (row&7)) folded into
// DMA src addrs -> conflict-free frag reads. B at-use from L2-hot WmX.
// Main loop ROLLED (unroll 1) to bound register live-range: no spill.
// LDS: AsL/WcS aliased onto As1 -> ~34KB.
// ---------------------------------------------------------------------------
__global__ __launch_bounds__(256, 3) void score_kernel(
    const float* __restrict__ values, const float* __restrict__ prev,
    const float* __restrict__ Wc, const float* __restrict__ Wv,
    const float* __restrict__ bv, const short* __restrict__ WmX,
    const short* __restrict__ WlX, const float* __restrict__ qb,
    float* __restrict__ scores)
{
    __shared__ char smem[2 * 16384 + 1024 + 512];
    float* As0 = (float*)smem;                      // 16 KB buf 0
    float* As1 = (float*)(smem + 16384);            // 16 KB buf 1
    short* AsL = (short*)(smem + 16384);            // alias on As1 (4 KB)
    float* WcS = (float*)(smem + 16384 + 4096);     // alias on As1 (3.9 KB)
    float* qbS = (float*)(smem + 32768);            // 1 KB
    float* WvS = (float*)(smem + 32768 + 1024);     // 0.5 KB

    const int tid = threadIdx.x;
    const int r0 = blockIdx.x * 64;
    const int b0 = r0 / T_;
    const int b1 = (r0 + 63) / T_;

    const int wv = tid >> 6, lane = tid & 63;
    const int quad = lane >> 4, m15 = lane & 15;
    const int row = wv * 16 + m15;
    const int lrow = lane >> 4;                     // staging: row within 4-row group

    const int4* bW  = (const int4*)WmX + m15 * 4 + quad;
    const int4* blW = (const int4*)WlX + m15 * 4 + quad;

    // staging source pointers (swizzle folded in). j in {0,1,2,3}:
    //   row = wv*16 + j*4 + lrow ; src unit lu = ((lane&15) + ((j&1)<<2)+lrow) & 15
    // -> LDS unit u of row r holds source unit (u + (r&7)) & 15.
    const int luE = (((lane & 15) + lrow) & 15);            // j even
    const int luO = (((lane & 15) + 4 + lrow) & 15);        // j odd
    const float* sE0 = values + (size_t)(r0 + wv * 16 + 0 + lrow) * DV_ + luE * 4;
    const float* sO0 = values + (size_t)(r0 + wv * 16 + 4 + lrow) * DV_ + luO * 4;
    const float* sE1 = sE0 + (size_t)8 * DV_;
    const float* sO1 = sO0 + (size_t)8 * DV_;
    const int ldsOff = wv * 16 * 64;   // floats; +256 per j

    // initial stage of window 0 into As0 — in flight across conv
    {
        gload_lds16(sE0, As0 + ldsOff);
        gload_lds16(sO0, As0 + ldsOff + 256);
        gload_lds16(sE1, As0 + ldsOff + 512);
        gload_lds16(sO1, As0 + ldsOff + 768);
    }

    for (int i = tid; i < KS_ * F_; i += 256) WcS[i] = Wc[i];
    if (tid < U_) WvS[tid] = Wv[tid];
    {
        int bb = (tid < U_) ? b0 : b1;
        qbS[tid] = qb[bb * U_ + (tid & (U_ - 1))];
    }
    __syncthreads();   // WcS/qbS/WvS ready (also drains As0 DMA)

    // location conv: loc_pre[i,f] = sum_k prev[b, t+k-15]*Wc[k,f] (SAME pad)
    {
        int i = tid & 63, fg = tid >> 6;
        int r = r0 + i;
        int b = r / T_;
        int t = r - b * T_;
        const float* pv = prev + b * T_;
        float a8[8] = {};
#pragma unroll
        for (int k = 0; k < KS_; ++k) {
            int tt = t + k - 15;
            float p = ((unsigned)tt < (unsigned)T_) ? pv[tt] : 0.f;
#pragma unroll
            for (int j = 0; j < 8; ++j) a8[j] += p * WcS[k * F_ + fg * 8 + j];
        }
        int4 pq;
        pq.x = pk2(a8[0], a8[1]); pq.y = pk2(a8[2], a8[3]);
        pq.z = pk2(a8[4], a8[5]); pq.w = pk2(a8[6], a8[7]);
        ((int4*)AsL)[i * 4 + (fg ^ ((i >> 1) & 3))] = pq;
    }
    __syncthreads();

    // loc GEMM (K=32) -> acc init = qb + tanh(loc)
    f32x4 acc[8] = {};
    {
        short8 afl = ((const short8*)AsL)[row * 4 + (quad ^ ((row >> 1) & 3))];
#pragma unroll
        for (int c = 0; c < 8; ++c) {
            int4 bl = blW[c * 64];
            acc[c] = __builtin_amdgcn_mfma_f32_16x16x32_bf16(afl, *(short8*)&bl, acc[c], 0, 0, 0);
        }
        int qoff[4];
#pragma unroll
        for (int v = 0; v < 4; ++v) {
            int r = r0 + wv * 16 + quad * 4 + v;
            qoff[v] = ((r / T_) == b0) ? 0 : U_;
        }
#pragma unroll
        for (int c = 0; c < 8; ++c) {
            int col = c * 16 + m15;
#pragma unroll
            for (int v = 0; v < 4; ++v)
                acc[c][v] = qbS[qoff[v] + col] + fast_tanh(acc[c][v]);
        }
    }
    __syncthreads();   // AsL/WcS reads done -> As1 region reusable

    // main loop: 8 steps x BK=64 (2 kc each); one barrier per step. ROLLED.
    const int Rr = m15 & 7;          // read-side rotation
    float* cur = As0;
    float* nxt = As1;
    const int4* bWs = bW;            // advances 512 int4 per kc
    int koff = 64;                   // next window start (floats)
#pragma unroll 1
    for (int s = 0; s < 8; ++s) {
        if (s < 7) {
            gload_lds16(sE0 + koff, nxt + ldsOff);
            gload_lds16(sO0 + koff, nxt + ldsOff + 256);
            gload_lds16(sE1 + koff, nxt + ldsOff + 512);
            gload_lds16(sO1 + koff, nxt + ldsOff + 768);
        }
        const float4* ap = (const float4*)(cur + row * 64);
#pragma unroll
        for (int kc = 0; kc < 2; ++kc) {
            int x = kc * 8 + quad * 2;
            float4 f0 = ap[(x - Rr) & 15];
            float4 f1 = ap[(x + 1 - Rr) & 15];
            short8 af = pk8(f0, f1);
            int4 bf[4];
#pragma unroll
            for (int c = 0; c < 4; ++c) bf[c] = bWs[c * 64];
#pragma unroll
            for (int c = 0; c < 4; ++c)
                acc[c] = __builtin_amdgcn_mfma_f32_16x16x32_bf16(af, *(short8*)&bf[c], acc[c], 0, 0, 0);
#pragma unroll
            for (int c = 0; c < 4; ++c) bf[c] = bWs[(c + 4) * 64];
#pragma unroll
            for (int c = 0; c < 4; ++c)
                acc[c + 4] = __builtin_amdgcn_mfma_f32_16x16x32_bf16(af, *(short8*)&bf[c], acc[c + 4], 0, 0, 0);
            bWs += 512;
        }
        __syncthreads();
        float* t = cur; cur = nxt; nxt = t;
        koff += 64;
    }

    // epilogue: score = sum_col tanh(acc)*Wv[col] + bv
    float psum[4] = {0.f, 0.f, 0.f, 0.f};
#pragma unroll
    for (int c = 0; c < 8; ++c) {
        int col = c * 16 + m15;
        float wvv = WvS[col];
#pragma unroll
        for (int v = 0; v < 4; ++v)
            psum[v] += fast_tanh(acc[c][v]) * wvv;
    }
#pragma unroll
    for (int off = 1; off < 16; off <<= 1) {
#pragma unroll
        for (int v = 0; v < 4; ++v) psum[v] += __shfl_xor(psum[v], off);
    }
    if (m15 == 0) {
        float bvv = bv[0];
#pragma unroll
        for (int v = 0; v < 4; ++v)
            scores[r0 + wv * 16 + quad * 4 + v] = psum[v] + bvv;
    }
}

// ---------------------------------------------------------------------------
// fused softmax + context partial. grid (64, 16). Each block recomputes the
// softmax stats from scores (L2-hot, 4KB), writes its attw t-slice, and
// accumulates partial context over its 63-t chunk.
// ---------------------------------------------------------------------------
__global__ __launch_bounds__(256) void ctxsm_kernel(
    const float* __restrict__ scores, const float* __restrict__ values,
    float* __restrict__ attw, float* __restrict__ part)
{
    __shared__ float sS[1024];
    __shared__ float red[4];
    __shared__ float4 ps[128];
    int b = blockIdx.x, p = blockIdx.y, tid = threadIdx.x;
    const float* sb = scores + b * T_;
    float v[4];
#pragma unroll
    for (int i = 0; i < 4; ++i) {
        int t = tid + i * 256;
        v[i] = (t < T_) ? sb[t] : -1e30f;
        sS[t] = v[i];
    }
    float mx = fmaxf(fmaxf(v[0], v[1]), fmaxf(v[2], v[3]));
#pragma unroll
    for (int off = 32; off >= 1; off >>= 1) mx = fmaxf(mx, __shfl_xor(mx, off));
    int wvi = tid >> 6, lane = tid & 63;
    if (lane == 0) red[wvi] = mx;
    __syncthreads();
    mx = fmaxf(fmaxf(red[0], red[1]), fmaxf(red[2], red[3]));
    float sum = 0.f;
#pragma unroll
    for (int i = 0; i < 4; ++i)
        sum += (tid + i * 256 < T_) ? __expf(v[i] - mx) : 0.f;
#pragma unroll
    for (int off = 32; off >= 1; off >>= 1) sum += __shfl_xor(sum, off);
    __syncthreads();
    if (lane == 0) red[wvi] = sum;
    __syncthreads();
    float inv = 1.0f / (red[0] + red[1] + red[2] + red[3]);

    int t0 = p * CT_;
    int len = (T_ - t0 < CT_) ? (T_ - t0) : CT_;
    if (tid < len) attw[b * T_ + t0 + tid] = __expf(sS[t0 + tid] - mx) * inv;

    int cl = tid & 127, tp = tid >> 7;
    const float* vp = values + ((size_t)b * T_ + t0) * DV_ + cl * 4;
    float4 a = {0.f, 0.f, 0.f, 0.f};
#pragma unroll 4
    for (int t = tp; t < len; t += 2) {
        float4 vv = *(const float4*)(vp + (size_t)t * DV_);
        float wt = __expf(sS[t0 + t] - mx) * inv;
        a.x += wt * vv.x; a.y += wt * vv.y; a.z += wt * vv.z; a.w += wt * vv.w;
    }
    if (tp == 1) ps[cl] = a;
    __syncthreads();
    if (tp == 0) {
        float4 o = ps[cl];
        o.x += a.x; o.y += a.y; o.z += a.z; o.w += a.w;
        *(float4*)(part + ((size_t)(b * P_ + p)) * DV_ + cl * 4) = o;
    }
}

// context phase 2: ctx[b,d] = sum_p partial[b,p,d]
__global__ void ctx2_kernel(const float* __restrict__ part, float* __restrict__ ctx) {
    int b = blockIdx.x, tid = threadIdx.x;   // 128 threads, float4 each
    const float* pp = part + (size_t)b * P_ * DV_ + tid * 4;
    float4 s = {0.f, 0.f, 0.f, 0.f};
#pragma unroll
    for (int p = 0; p < P_; ++p) {
        float4 v = *(const float4*)(pp + (size_t)p * DV_);
        s.x += v.x; s.y += v.y; s.z += v.z; s.w += v.w;
    }
    *(float4*)(ctx + (size_t)b * DV_ + tid * 4) = s;
}

extern "C" void kernel_launch(void* const* d_in, const int* in_sizes, int n_in,
                              void* d_out, int out_size, void* d_ws, size_t ws_size,
                              hipStream_t stream) {
    const float* query  = (const float*)d_in[0];
    const float* values = (const float*)d_in[1];
    const float* prev   = (const float*)d_in[2];
    const float* Wq     = (const float*)d_in[3];
    const float* bq     = (const float*)d_in[4];
    const float* Wm     = (const float*)d_in[5];
    const float* bm     = (const float*)d_in[6];
    const float* Wv     = (const float*)d_in[7];
    const float* bv     = (const float*)d_in[8];
    const float* Wc     = (const float*)d_in[9];
    const float* Wl     = (const float*)d_in[10];

    float* out  = (float*)d_out;
    float* ctx  = out;                 // [64,512]
    float* attw = out + B_ * DV_;      // [64,1000,1]

    char* ws = (char*)d_ws;
    float* qb     = (float*)(ws);                              // 32768 B
    float* scores = (float*)(ws + 32768);                      // 256000 B
    short* WmX    = (short*)(ws + 288768);                     // 131072 B
    short* WlX    = (short*)(ws + 419840);                     // 8192 B
    float* part   = (float*)(ws + 428032);                     // 2 MB

    prep_qb_kernel<<<73, 1024, 0, stream>>>(Wm, Wl, query, Wq, bq, bm, WmX, WlX, qb);
    score_kernel<<<1000, 256, 0, stream>>>(values, prev, Wc, Wv, bv, WmX, WlX, qb, scores);
    ctxsm_kernel<<<dim3(B_, P_), 256, 0, stream>>>(scores, values, attw, part);
    ctx2_kernel<<<B_, 128, 0, stream>>>(part, ctx);
}

// Round 7
// 288.260 us; speedup vs baseline: 1.1715x; 1.1052x over previous
//
#include <hip/hip_runtime.h>

#define B_  64
#define T_  1000
#define DV_ 512
#define DQ_ 1024
#define U_  128
#define F_  32
#define KS_ 31
#define P_  25     // context partial chunks per batch
#define CT_ 40     // t per chunk (25*40 = 1000 exactly)

typedef __attribute__((ext_vector_type(8))) short short8;
typedef __attribute__((ext_vector_type(4))) float f32x4;

// round-to-nearest-even f32 -> bf16 (bit trick), packed pair
__device__ __forceinline__ unsigned pk2(float a, float b) {
    union { float f; unsigned u; } x, y;
    x.f = a; y.f = b;
    unsigned ra = (x.u + 0x7FFFu + ((x.u >> 16) & 1u)) >> 16;
    unsigned rb = (y.u + 0x7FFFu + ((y.u >> 16) & 1u)) >> 16;
    return (ra & 0xFFFFu) | (rb << 16);
}

__device__ __forceinline__ float fast_tanh(float x) {
    return 1.0f - 2.0f / (__expf(2.0f * x) + 1.0f);
}

// pack two float4 (8 consecutive k) into bf16 short8
__device__ __forceinline__ short8 pk8(float4 f0, float4 f1) {
    int4 q;
    q.x = pk2(f0.x, f0.y); q.y = pk2(f0.z, f0.w);
    q.z = pk2(f1.x, f1.y); q.w = pk2(f1.z, f1.w);
    return *(short8*)&q;
}

// async global->LDS DMA, 16B per lane; LDS dest is wave-uniform base + lane*16
__device__ __forceinline__ void gload_lds16(const void* g, void* l) {
    __builtin_amdgcn_global_load_lds(
        (const __attribute__((address_space(1))) unsigned*)g,
        (__attribute__((address_space(3))) unsigned*)l, 16, 0, 0);
}

// ---------------------------------------------------------------------------
// Merged: prep (repack Wm/Wl to bf16 B-frag layout) + qb (query proj).
// Blocks 0..8: prep. Blocks 9..72: qb for b = blk-9.
// ---------------------------------------------------------------------------
__global__ __launch_bounds__(1024) void prep_qb_kernel(
    const float* __restrict__ Wm, const float* __restrict__ Wl,
    const float* __restrict__ query, const float* __restrict__ Wq,
    const float* __restrict__ bq, const float* __restrict__ bm,
    short* __restrict__ WmX, short* __restrict__ WlX, float* __restrict__ qb)
{
    __shared__ float sh[DQ_ + 8 * U_];
    int blk = blockIdx.x, tid = threadIdx.x;
    if (blk < 9) {
        int g = blk * 1024 + tid;
        if (g < 8192) {
            int kc = g >> 9, e = g & 511;
            int n = e >> 2, q = e & 3;
            int kb = kc * 32 + q * 8;
            int4 p;
            p.x = pk2(Wm[(kb + 0) * U_ + n], Wm[(kb + 1) * U_ + n]);
            p.y = pk2(Wm[(kb + 2) * U_ + n], Wm[(kb + 3) * U_ + n]);
            p.z = pk2(Wm[(kb + 4) * U_ + n], Wm[(kb + 5) * U_ + n]);
            p.w = pk2(Wm[(kb + 6) * U_ + n], Wm[(kb + 7) * U_ + n]);
            ((int4*)WmX)[g] = p;
        } else if (g < 8704) {
            int e = g - 8192;
            int n = e >> 2, q = e & 3;
            int kb = q * 8;
            int4 p;
            p.x = pk2(Wl[(kb + 0) * U_ + n], Wl[(kb + 1) * U_ + n]);
            p.y = pk2(Wl[(kb + 2) * U_ + n], Wl[(kb + 3) * U_ + n]);
            p.z = pk2(Wl[(kb + 4) * U_ + n], Wl[(kb + 5) * U_ + n]);
            p.w = pk2(Wl[(kb + 6) * U_ + n], Wl[(kb + 7) * U_ + n]);
            ((int4*)WlX)[e] = p;
        }
    } else {
        float* qs = sh;
        float* red = sh + DQ_;
        int b = blk - 9;
        qs[tid] = query[b * DQ_ + tid];
        __syncthreads();
        int u = tid & 127, p = tid >> 7;
        float a = 0.f;
        const float* wp = Wq + (size_t)p * 128 * U_ + u;
        const float* qp = qs + p * 128;
#pragma unroll 8
        for (int k = 0; k < 128; ++k) a += qp[k] * wp[(size_t)k * U_];
        red[p * U_ + u] = a;
        __syncthreads();
        if (tid < U_) {
            float s = bq[tid] + bm[tid];
#pragma unroll
            for (int pp = 0; pp < 8; ++pp) s += red[pp * U_ + tid];
            qb[b * U_ + tid] = s;
        }
    }
}

// ---------------------------------------------------------------------------
// scores[r], r=b*T+t: tanh(values@Wm + qb + tanh(conv(prev)@Wl)) @ Wv + bv
// M=64/block (1000 blocks). A staged fp32 via global_load_lds (16B units),
// double-buffered BK=64 tiles, rotation swizzle (unit + (row&7)) folded into
// DMA src addrs -> conflict-free frag reads. B at-use from L2-hot WmX.
// NO min-waves bound: let the allocator keep the full live set in regs
// (R4-R6 showed forced caps (64/84 arch VGPRs) spill ~150-220 MB to scratch).
// ---------------------------------------------------------------------------
__global__ __launch_bounds__(256) void score_kernel(
    const float* __restrict__ values, const float* __restrict__ prev,
    const float* __restrict__ Wc, const float* __restrict__ Wv,
    const float* __restrict__ bv, const short* __restrict__ WmX,
    const short* __restrict__ WlX, const float* __restrict__ qb,
    float* __restrict__ scores)
{
    __shared__ char smem[2 * 16384 + 1024 + 512];
    float* As0 = (float*)smem;                      // 16 KB buf 0
    float* As1 = (float*)(smem + 16384);            // 16 KB buf 1
    short* AsL = (short*)(smem + 16384);            // alias on As1 (4 KB)
    float* WcS = (float*)(smem + 16384 + 4096);     // alias on As1 (3.9 KB)
    float* qbS = (float*)(smem + 32768);            // 1 KB
    float* WvS = (float*)(smem + 32768 + 1024);     // 0.5 KB

    const int tid = threadIdx.x;
    const int r0 = blockIdx.x * 64;
    const int b0 = r0 / T_;
    const int b1 = (r0 + 63) / T_;

    const int wv = tid >> 6, lane = tid & 63;
    const int quad = lane >> 4, m15 = lane & 15;
    const int row = wv * 16 + m15;
    const int lrow = lane >> 4;                     // staging: row within 4-row group

    const int4* bW  = (const int4*)WmX + m15 * 4 + quad;
    const int4* blW = (const int4*)WlX + m15 * 4 + quad;

    // staging source pointers (swizzle folded in). j in {0,1,2,3}:
    //   row = wv*16 + j*4 + lrow ; src unit lu = ((lane&15) + ((j&1)<<2)+lrow) & 15
    // -> LDS unit u of row r holds source unit (u + (r&7)) & 15.
    const int luE = (((lane & 15) + lrow) & 15);            // j even
    const int luO = (((lane & 15) + 4 + lrow) & 15);        // j odd
    const float* sE0 = values + (size_t)(r0 + wv * 16 + 0 + lrow) * DV_ + luE * 4;
    const float* sO0 = values + (size_t)(r0 + wv * 16 + 4 + lrow) * DV_ + luO * 4;
    const float* sE1 = sE0 + (size_t)8 * DV_;
    const float* sO1 = sO0 + (size_t)8 * DV_;
    const int ldsOff = wv * 16 * 64;   // floats; +256 per j

    // initial stage of window 0 into As0 — in flight across conv
    {
        gload_lds16(sE0, As0 + ldsOff);
        gload_lds16(sO0, As0 + ldsOff + 256);
        gload_lds16(sE1, As0 + ldsOff + 512);
        gload_lds16(sO1, As0 + ldsOff + 768);
    }

    for (int i = tid; i < KS_ * F_; i += 256) WcS[i] = Wc[i];
    if (tid < U_) WvS[tid] = Wv[tid];
    {
        int bb = (tid < U_) ? b0 : b1;
        qbS[tid] = qb[bb * U_ + (tid & (U_ - 1))];
    }
    __syncthreads();   // WcS/qbS/WvS ready (also drains As0 DMA)

    // location conv: loc_pre[i,f] = sum_k prev[b, t+k-15]*Wc[k,f] (SAME pad)
    {
        int i = tid & 63, fg = tid >> 6;
        int r = r0 + i;
        int b = r / T_;
        int t = r - b * T_;
        const float* pv = prev + b * T_;
        float a8[8] = {};
#pragma unroll
        for (int k = 0; k < KS_; ++k) {
            int tt = t + k - 15;
            float p = ((unsigned)tt < (unsigned)T_) ? pv[tt] : 0.f;
#pragma unroll
            for (int j = 0; j < 8; ++j) a8[j] += p * WcS[k * F_ + fg * 8 + j];
        }
        int4 pq;
        pq.x = pk2(a8[0], a8[1]); pq.y = pk2(a8[2], a8[3]);
        pq.z = pk2(a8[4], a8[5]); pq.w = pk2(a8[6], a8[7]);
        ((int4*)AsL)[i * 4 + (fg ^ ((i >> 1) & 3))] = pq;
    }
    __syncthreads();

    // loc GEMM (K=32) -> acc init = qb + tanh(loc)
    f32x4 acc[8] = {};
    {
        short8 afl = ((const short8*)AsL)[row * 4 + (quad ^ ((row >> 1) & 3))];
#pragma unroll
        for (int c = 0; c < 8; ++c) {
            int4 bl = blW[c * 64];
            acc[c] = __builtin_amdgcn_mfma_f32_16x16x32_bf16(afl, *(short8*)&bl, acc[c], 0, 0, 0);
        }
        int qoff[4];
#pragma unroll
        for (int v = 0; v < 4; ++v) {
            int r = r0 + wv * 16 + quad * 4 + v;
            qoff[v] = ((r / T_) == b0) ? 0 : U_;
        }
#pragma unroll
        for (int c = 0; c < 8; ++c) {
            int col = c * 16 + m15;
#pragma unroll
            for (int v = 0; v < 4; ++v)
                acc[c][v] = qbS[qoff[v] + col] + fast_tanh(acc[c][v]);
        }
    }
    __syncthreads();   // AsL/WcS reads done -> As1 region reusable

    // main loop: 8 steps x BK=64 (2 kc each); one barrier per step. ROLLED.
    const int Rr = m15 & 7;          // read-side rotation
    float* cur = As0;
    float* nxt = As1;
    const int4* bWs = bW;            // advances 512 int4 per kc
    int koff = 64;                   // next window start (floats)
#pragma unroll 1
    for (int s = 0; s < 8; ++s) {
        if (s < 7) {
            gload_lds16(sE0 + koff, nxt + ldsOff);
            gload_lds16(sO0 + koff, nxt + ldsOff + 256);
            gload_lds16(sE1 + koff, nxt + ldsOff + 512);
            gload_lds16(sO1 + koff, nxt + ldsOff + 768);
        }
        const float4* ap = (const float4*)(cur + row * 64);
#pragma unroll
        for (int kc = 0; kc < 2; ++kc) {
            int x = kc * 8 + quad * 2;
            float4 f0 = ap[(x - Rr) & 15];
            float4 f1 = ap[(x + 1 - Rr) & 15];
            short8 af = pk8(f0, f1);
            int4 bf[4];
#pragma unroll
            for (int c = 0; c < 4; ++c) bf[c] = bWs[c * 64];
#pragma unroll
            for (int c = 0; c < 4; ++c)
                acc[c] = __builtin_amdgcn_mfma_f32_16x16x32_bf16(af, *(short8*)&bf[c], acc[c], 0, 0, 0);
#pragma unroll
            for (int c = 0; c < 4; ++c) bf[c] = bWs[(c + 4) * 64];
#pragma unroll
            for (int c = 0; c < 4; ++c)
                acc[c + 4] = __builtin_amdgcn_mfma_f32_16x16x32_bf16(af, *(short8*)&bf[c], acc[c + 4], 0, 0, 0);
            bWs += 512;
        }
        __syncthreads();
        float* t = cur; cur = nxt; nxt = t;
        koff += 64;
    }

    // epilogue: score = sum_col tanh(acc)*Wv[col] + bv
    float psum[4] = {0.f, 0.f, 0.f, 0.f};
#pragma unroll
    for (int c = 0; c < 8; ++c) {
        int col = c * 16 + m15;
        float wvv = WvS[col];
#pragma unroll
        for (int v = 0; v < 4; ++v)
            psum[v] += fast_tanh(acc[c][v]) * wvv;
    }
#pragma unroll
    for (int off = 1; off < 16; off <<= 1) {
#pragma unroll
        for (int v = 0; v < 4; ++v) psum[v] += __shfl_xor(psum[v], off);
    }
    if (m15 == 0) {
        float bvv = bv[0];
#pragma unroll
        for (int v = 0; v < 4; ++v)
            scores[r0 + wv * 16 + quad * 4 + v] = psum[v] + bvv;
    }
}

// ---------------------------------------------------------------------------
// fused softmax + context partial. grid (64, 25). Each block recomputes the
// softmax stats from scores (L2-hot, 4KB), writes its attw t-slice, and
// accumulates partial context over its 40-t chunk.
// ---------------------------------------------------------------------------
__global__ __launch_bounds__(256) void ctxsm_kernel(
    const float* __restrict__ scores, const float* __restrict__ values,
    float* __restrict__ attw, float* __restrict__ part)
{
    __shared__ float sS[1024];
    __shared__ float red[4];
    __shared__ float4 ps[128];
    int b = blockIdx.x, p = blockIdx.y, tid = threadIdx.x;
    const float* sb = scores + b * T_;
    float v[4];
#pragma unroll
    for (int i = 0; i < 4; ++i) {
        int t = tid + i * 256;
        v[i] = (t < T_) ? sb[t] : -1e30f;
        sS[t] = v[i];
    }
    float mx = fmaxf(fmaxf(v[0], v[1]), fmaxf(v[2], v[3]));
#pragma unroll
    for (int off = 32; off >= 1; off >>= 1) mx = fmaxf(mx, __shfl_xor(mx, off));
    int wvi = tid >> 6, lane = tid & 63;
    if (lane == 0) red[wvi] = mx;
    __syncthreads();
    mx = fmaxf(fmaxf(red[0], red[1]), fmaxf(red[2], red[3]));
    float sum = 0.f;
#pragma unroll
    for (int i = 0; i < 4; ++i)
        sum += (tid + i * 256 < T_) ? __expf(v[i] - mx) : 0.f;
#pragma unroll
    for (int off = 32; off >= 1; off >>= 1) sum += __shfl_xor(sum, off);
    __syncthreads();
    if (lane == 0) red[wvi] = sum;
    __syncthreads();
    float inv = 1.0f / (red[0] + red[1] + red[2] + red[3]);

    int t0 = p * CT_;
    if (tid < CT_) attw[b * T_ + t0 + tid] = __expf(sS[t0 + tid] - mx) * inv;

    int cl = tid & 127, tp = tid >> 7;
    const float* vp = values + ((size_t)b * T_ + t0) * DV_ + cl * 4;
    float4 a = {0.f, 0.f, 0.f, 0.f};
#pragma unroll 4
    for (int t = tp; t < CT_; t += 2) {
        float4 vv = *(const float4*)(vp + (size_t)t * DV_);
        float wt = __expf(sS[t0 + t] - mx) * inv;
        a.x += wt * vv.x; a.y += wt * vv.y; a.z += wt * vv.z; a.w += wt * vv.w;
    }
    if (tp == 1) ps[cl] = a;
    __syncthreads();
    if (tp == 0) {
        float4 o = ps[cl];
        o.x += a.x; o.y += a.y; o.z += a.z; o.w += a.w;
        *(float4*)(part + ((size_t)(b * P_ + p)) * DV_ + cl * 4) = o;
    }
}

// context phase 2: ctx[b,d] = sum_p partial[b,p,d]
__global__ void ctx2_kernel(const float* __restrict__ part, float* __restrict__ ctx) {
    int b = blockIdx.x, tid = threadIdx.x;   // 128 threads, float4 each
    const float* pp = part + (size_t)b * P_ * DV_ + tid * 4;
    float4 s = {0.f, 0.f, 0.f, 0.f};
#pragma unroll
    for (int p = 0; p < P_; ++p) {
        float4 v = *(const float4*)(pp + (size_t)p * DV_);
        s.x += v.x; s.y += v.y; s.z += v.z; s.w += v.w;
    }
    *(float4*)(ctx + (size_t)b * DV_ + tid * 4) = s;
}

extern "C" void kernel_launch(void* const* d_in, const int* in_sizes, int n_in,
                              void* d_out, int out_size, void* d_ws, size_t ws_size,
                              hipStream_t stream) {
    const float* query  = (const float*)d_in[0];
    const float* values = (const float*)d_in[1];
    const float* prev   = (const float*)d_in[2];
    const float* Wq     = (const float*)d_in[3];
    const float* bq     = (const float*)d_in[4];
    const float* Wm     = (const float*)d_in[5];
    const float* bm     = (const float*)d_in[6];
    const float* Wv     = (const float*)d_in[7];
    const float* bv     = (const float*)d_in[8];
    const float* Wc     = (const float*)d_in[9];
    const float* Wl     = (const float*)d_in[10];

    float* out  = (float*)d_out;
    float* ctx  = out;                 // [64,512]
    float* attw = out + B_ * DV_;      // [64,1000,1]

    char* ws = (char*)d_ws;
    float* qb     = (float*)(ws);                              // 32768 B
    float* scores = (float*)(ws + 32768);                      // 256000 B
    short* WmX    = (short*)(ws + 288768);                     // 131072 B
    short* WlX    = (short*)(ws + 419840);                     // 8192 B
    float* part   = (float*)(ws + 428032);                     // 3.3 MB (25*64*512*4)

    prep_qb_kernel<<<73, 1024, 0, stream>>>(Wm, Wl, query, Wq, bq, bm, WmX, WlX, qb);
    score_kernel<<<1000, 256, 0, stream>>>(values, prev, Wc, Wv, bv, WmX, WlX, qb, scores);
    ctxsm_kernel<<<dim3(B_, P_), 256, 0, stream>>>(scores, values, attw, part);
    ctx2_kernel<<<B_, 128, 0, stream>>>(part, ctx);
}